// Round 5
// baseline (354.950 us; speedup 1.0000x reference)
//
#include <hip/hip_runtime.h>
#include <cfloat>
#include <cstdint>

#define GBM 64
#define GBN 64
#define GBK 64
#define GPAD 68     // 68*4=272B rows: 16B-aligned for b128 frags
#define DSPLIT 8
#define ROWG 16

typedef unsigned int u32;

__device__ __forceinline__ void gload_lds16(const float* g, float* l) {
    __builtin_amdgcn_global_load_lds(
        (const __attribute__((address_space(1))) u32*)g,
        (__attribute__((address_space(3))) u32*)l, 16, 0, 0);
}

// ---- split-K GEMM: py[s][M][N] partial of A[M,K] @ B[K,N], one 64^3 tile/block
__global__ __launch_bounds__(256) void gemm_splitk(
    const float* __restrict__ A, const float* __restrict__ B,
    float* __restrict__ Cpart, int M, int N, int K)
{
    __shared__ __align__(16) float Asm[GBK][GPAD];  // [kk][m]
    __shared__ __align__(16) float Bsm[GBK][GPAD];  // [kk][n]
    int t  = threadIdx.x;
    int m0 = blockIdx.y * GBM, n0 = blockIdx.x * GBN;
    int ks = blockIdx.z * GBK;

    #pragma unroll
    for (int i = 0; i < 4; i++) {
        int v = t + 256 * i;
        int m = v >> 4, k4 = (v & 15) * 4;
        float4 x = *(const float4*)&A[(size_t)(m0 + m) * K + ks + k4];
        Asm[k4 + 0][m] = x.x; Asm[k4 + 1][m] = x.y;
        Asm[k4 + 2][m] = x.z; Asm[k4 + 3][m] = x.w;
    }
    #pragma unroll
    for (int i = 0; i < 4; i++) {
        int v = t + 256 * i;
        int r = v >> 4, c4 = (v & 15) * 4;
        *(float4*)&Bsm[r][c4] = *(const float4*)&B[(size_t)(ks + r) * N + n0 + c4];
    }
    __syncthreads();

    int r4 = (t >> 4) * 4, c4 = (t & 15) * 4;
    float acc[4][4] = {{0.f}};
    #pragma unroll
    for (int kk = 0; kk < GBK; kk++) {
        float4 a = *(const float4*)&Asm[kk][r4];
        float4 b = *(const float4*)&Bsm[kk][c4];
        float av[4] = {a.x, a.y, a.z, a.w};
        float bv[4] = {b.x, b.y, b.z, b.w};
        #pragma unroll
        for (int i = 0; i < 4; i++)
            #pragma unroll
            for (int j = 0; j < 4; j++) acc[i][j] += av[i] * bv[j];
    }
    float* Cp = Cpart + (size_t)blockIdx.z * M * N;
    #pragma unroll
    for (int i = 0; i < 4; i++) {
        float4 v = {acc[i][0], acc[i][1], acc[i][2], acc[i][3]};
        *(float4*)&Cp[(size_t)(m0 + r4 + i) * N + n0 + c4] = v;
    }
}

// ---- gemm2 fused: pz[s][M][N] partial of (sum_s py + b_ts)[M,K] @ W[N,K]^T ----
__global__ __launch_bounds__(256) void gemm2_fused(
    const float* __restrict__ py, const float* __restrict__ b_ts,
    const float* __restrict__ W, float* __restrict__ pz,
    int M, int N, int K, int S)
{
    __shared__ __align__(16) float Asm[GBK][GPAD];  // [kk][m], kk = h in slice
    __shared__ __align__(16) float Bsm[GBK][GPAD];  // [kk][n]
    int t  = threadIdx.x;
    int m0 = blockIdx.y * GBM, n0 = blockIdx.x * GBN;
    int ks = blockIdx.z * GBK;

    #pragma unroll
    for (int i = 0; i < 4; i++) {                    // A = reduced y tile
        int v = t + 256 * i;
        int m = v >> 4, h4 = (v & 15) * 4;
        float4 x = *(const float4*)&b_ts[ks + h4];
        for (int s = 0; s < S; s++) {
            float4 p = *(const float4*)&py[((size_t)s * M + m0 + m) * K + ks + h4];
            x.x += p.x; x.y += p.y; x.z += p.z; x.w += p.w;
        }
        Asm[h4 + 0][m] = x.x; Asm[h4 + 1][m] = x.y;
        Asm[h4 + 2][m] = x.z; Asm[h4 + 3][m] = x.w;
    }
    #pragma unroll
    for (int i = 0; i < 4; i++) {                    // B^T tile
        int v = t + 256 * i;
        int n = v >> 4, k4 = (v & 15) * 4;
        float4 x = *(const float4*)&W[(size_t)(n0 + n) * K + ks + k4];
        Bsm[k4 + 0][n] = x.x; Bsm[k4 + 1][n] = x.y;
        Bsm[k4 + 2][n] = x.z; Bsm[k4 + 3][n] = x.w;
    }
    __syncthreads();

    int r4 = (t >> 4) * 4, c4 = (t & 15) * 4;
    float acc[4][4] = {{0.f}};
    #pragma unroll
    for (int kk = 0; kk < GBK; kk++) {
        float4 a = *(const float4*)&Asm[kk][r4];
        float4 b = *(const float4*)&Bsm[kk][c4];
        float av[4] = {a.x, a.y, a.z, a.w};
        float bv[4] = {b.x, b.y, b.z, b.w};
        #pragma unroll
        for (int i = 0; i < 4; i++)
            #pragma unroll
            for (int j = 0; j < 4; j++) acc[i][j] += av[i] * bv[j];
    }
    float* Cp = pz + (size_t)blockIdx.z * M * N;
    #pragma unroll
    for (int i = 0; i < 4; i++) {
        float4 v = {acc[i][0], acc[i][1], acc[i][2], acc[i][3]};
        *(float4*)&Cp[(size_t)(m0 + r4 + i) * N + n0 + c4] = v;
    }
}

// ---- feat.z partial dot + fused last-block finalize ------------------------
__global__ __launch_bounds__(256) void feat_final(
    const float* __restrict__ feat, const float* __restrict__ pz,
    float* __restrict__ s_part, int* __restrict__ cnt,
    const float* __restrict__ boxes, const float* __restrict__ masks,
    const float* __restrict__ py, const float* __restrict__ b_ts,
    const float* __restrict__ b_vs, const int* __restrict__ kptr,
    float* __restrict__ out_box, float* __restrict__ out_mask,
    float* __restrict__ out_max,
    int G, int D, int bs, int S, int AN, int CH, int CM, int H)
{
    __shared__ union {
        float4 bufv[2][676];
        struct {
            float ms[176]; int selg[176]; float simv[176];
            float redw[4]; float bb; int sel[2];
        } f;
    } sh;
    __shared__ __align__(16) float zs[128];
    __shared__ int lastf;

    const int b = blockIdx.y, ds = blockIdx.x;
    const int dchunk = D / DSPLIT;          // 128
    const int ngrp = dchunk / ROWG;         // 8
    const int grpVec = ROWG * G / 4;        // 676 float4 per group
    int t  = threadIdx.x;
    int wb = t & ~63;                       // wave-uniform base

    if (t < dchunk) {
        float s = 0.f;
        #pragma unroll
        for (int sp = 0; sp < DSPLIT; sp++)
            s += pz[((size_t)sp * bs + b) * D + ds * dchunk + t];
        zs[t] = s;
    }

    const float* gsrc = feat + ((size_t)b * D + (size_t)ds * dchunk) * G;
    {   // prologue: DMA group 0 into buffer 0
        float* dst = (float*)sh.bufv[0];
        gload_lds16(gsrc + 4 * t,         dst + 4 * wb);
        gload_lds16(gsrc + 4 * (t + 256), dst + 4 * (wb + 256));
        if (t + 512 < grpVec)
            gload_lds16(gsrc + 4 * (t + 512), dst + 4 * (wb + 512));
    }
    __syncthreads();

    float acc = 0.f;
    int cur = 0;
    for (int gi = 0; gi < ngrp; gi++) {
        if (gi + 1 < ngrp) {
            const float* gs = gsrc + (size_t)(gi + 1) * (grpVec * 4);
            float* dst = (float*)sh.bufv[cur ^ 1];
            gload_lds16(gs + 4 * t,         dst + 4 * wb);
            gload_lds16(gs + 4 * (t + 256), dst + 4 * (wb + 256));
            if (t + 512 < grpVec)
                gload_lds16(gs + 4 * (t + 512), dst + 4 * (wb + 512));
        }
        if (t < G) {
            const float* bp = (const float*)sh.bufv[cur];
            #pragma unroll
            for (int r4 = 0; r4 < ROWG / 4; r4++) {
                float4 zv = *(const float4*)&zs[gi * ROWG + r4 * 4];
                acc += bp[(r4 * 4 + 0) * G + t] * zv.x;
                acc += bp[(r4 * 4 + 1) * G + t] * zv.y;
                acc += bp[(r4 * 4 + 2) * G + t] * zv.z;
                acc += bp[(r4 * 4 + 3) * G + t] * zv.w;
            }
        }
        __syncthreads();
        cur ^= 1;
    }
    if (t < G) s_part[((size_t)b * G + t) * DSPLIT + ds] = acc;

    // ---- last-block-done handoff ----
    __threadfence();
    __syncthreads();
    if (t == 0) lastf = (atomicAdd(&cnt[b], 1) == DSPLIT - 1);
    __syncthreads();
    if (!lastf) return;
    __threadfence();   // acquire: make other blocks' s_part visible

    // ---- finalize for batch b (LDS reused via union; all staging reads done)
    int k = *kptr; if (k > G) k = G;

    if (t < G) {
        const float* bp = boxes + (size_t)(b * G + t) * AN * CH;
        float s = 0.f;
        for (int a = 0; a < AN; a++) s += bp[a * CH + 4];
        sh.f.ms[t] = s / (float)AN;
    }
    // bb = b_vs . (sum_s py[s][b] + b_ts)
    float part = 0.f;
    for (int h = t; h < H; h += 256) {
        float yv = b_ts[h];
        for (int s = 0; s < S; s++) yv += py[((size_t)s * bs + b) * H + h];
        part += b_vs[h] * yv;
    }
    #pragma unroll
    for (int off = 32; off > 0; off >>= 1) part += __shfl_down(part, off);
    if ((t & 63) == 0) sh.f.redw[t >> 6] = part;
    __syncthreads();
    if (t == 0) sh.f.bb = sh.f.redw[0] + sh.f.redw[1] + sh.f.redw[2] + sh.f.redw[3];

    // exact top-k via rank (value desc, index asc) -- matches lax.top_k ties
    if (t < G) {
        float mv = sh.f.ms[t];
        int rank = 0;
        for (int g = 0; g < G; g++) {
            float o = sh.f.ms[g];
            rank += (int)((o > mv) | ((o == mv) & (g < t)));
        }
        if (rank < k) sh.f.selg[rank] = t;
    }
    __syncthreads();

    if (t < k) {
        const float* sp = s_part + ((size_t)b * G + sh.f.selg[t]) * DSPLIT;
        float s = 0.f;
        #pragma unroll
        for (int i = 0; i < DSPLIT; i++) s += sp[i];
        sh.f.simv[t] = s;
    }
    __syncthreads();

    if (t == 0) {
        float best = -FLT_MAX; int br = 0;
        for (int r = 0; r < k; r++) if (sh.f.simv[r] > best) { best = sh.f.simv[r]; br = r; }
        int gs = sh.f.selg[br];
        const float* bp = boxes + (size_t)(b * G + gs) * AN * CH;
        float bo = -FLT_MAX; int ai = 0;
        for (int a = 0; a < AN; a++) { float o = bp[a * CH + 4]; if (o > bo) { bo = o; ai = a; } }
        float cx = bp[ai * CH + 0], cy = bp[ai * CH + 1];
        float w  = bp[ai * CH + 2], hh = bp[ai * CH + 3];
        float x1 = cx - w * 0.5f, y1 = cy - hh * 0.5f;
        out_box[(size_t)b * CH + 0] = x1;
        out_box[(size_t)b * CH + 1] = y1;
        out_box[(size_t)b * CH + 2] = x1 + w;
        out_box[(size_t)b * CH + 3] = y1 + hh;
        for (int c = 4; c < CH; c++) out_box[(size_t)b * CH + c] = bp[ai * CH + c];
        out_max[b] = best + sh.f.bb;
        sh.f.sel[0] = gs; sh.f.sel[1] = ai;
    }
    __syncthreads();
    if (t < CM) {
        out_mask[(size_t)b * CM + t] =
            masks[((size_t)(b * G + sh.f.sel[0]) * AN + sh.f.sel[1]) * CM + t];
    }
}

extern "C" void kernel_launch(void* const* d_in, const int* in_sizes, int n_in,
                              void* d_out, int out_size, void* d_ws, size_t ws_size,
                              hipStream_t stream)
{
    const float* boxes = (const float*)d_in[0];
    const float* masks = (const float*)d_in[1];
    const float* feat  = (const float*)d_in[2];
    const float* lang  = (const float*)d_in[3];
    const float* W_vs  = (const float*)d_in[4];
    const float* b_vs  = (const float*)d_in[5];
    const float* W_ts  = (const float*)d_in[6];
    const float* b_ts  = (const float*)d_in[7];
    const int*   kptr  = (const int*)d_in[8];

    int H  = in_sizes[5];                 // 512
    int D  = in_sizes[4] / H;             // 1024
    int bs = in_sizes[3] / H;             // 256
    int G  = in_sizes[2] / (bs * D);      // 169
    int AN = 3;
    int CH = in_sizes[0] / (bs * G * AN); // 5
    int CM = in_sizes[1] / (bs * G * AN); // 32
    const int S = 8;                      // split-K slices (K = 512 = S*64)

    float* py     = (float*)d_ws;                       // S*bs*H
    float* pz     = py + (size_t)S * bs * H;            // S*bs*D
    float* s_part = pz + (size_t)S * bs * D;            // bs*G*DSPLIT
    int*   cnt    = (int*)(s_part + (size_t)bs * G * DSPLIT);  // bs ints

    float* out_box  = (float*)d_out;
    float* out_mask = out_box + (size_t)bs * CH;
    float* out_max  = out_mask + (size_t)bs * CM;

    hipMemsetAsync(cnt, 0, bs * sizeof(int), stream);

    // py = split-K partials of lang @ W_ts
    dim3 g1(H / GBN, bs / GBM, S);
    gemm_splitk<<<g1, 256, 0, stream>>>(lang, W_ts, py, bs, H, H);
    // pz = split-K partials of (sum py + b_ts) @ W_vs^T
    dim3 g2(D / GBN, bs / GBM, S);
    gemm2_fused<<<g2, 256, 0, stream>>>(py, b_ts, W_vs, pz, bs, D, H, S);
    // feat.z + fused finalize
    dim3 gC(DSPLIT, bs);
    feat_final<<<gC, 256, 0, stream>>>(feat, pz, s_part, cnt,
                                       boxes, masks, py, b_ts, b_vs, kptr,
                                       out_box, out_mask, out_max,
                                       G, D, bs, S, AN, CH, CM, H);
}

// Round 6
// 71.168 us; speedup vs baseline: 4.9875x; 4.9875x over previous
//
#include <hip/hip_runtime.h>
#include <cfloat>
#include <cstdint>

#define GBM 64
#define GBN 64
#define GBK 64
#define GPAD 68     // 68*4=272B rows: 16B-aligned for b128 frags
#define DSPLIT 8
#define ROWG 16

typedef unsigned int u32;

__device__ __forceinline__ void gload_lds16(const float* g, float* l) {
    __builtin_amdgcn_global_load_lds(
        (const __attribute__((address_space(1))) u32*)g,
        (__attribute__((address_space(3))) u32*)l, 16, 0, 0);
}

// ---- split-K GEMM: py[s][M][N] partial of A[M,K] @ B[K,N], one 64^3 tile/block
__global__ __launch_bounds__(256) void gemm_splitk(
    const float* __restrict__ A, const float* __restrict__ B,
    float* __restrict__ Cpart, int M, int N, int K)
{
    __shared__ __align__(16) float Asm[GBK][GPAD];  // [kk][m]
    __shared__ __align__(16) float Bsm[GBK][GPAD];  // [kk][n]
    int t  = threadIdx.x;
    int m0 = blockIdx.y * GBM, n0 = blockIdx.x * GBN;
    int ks = blockIdx.z * GBK;

    #pragma unroll
    for (int i = 0; i < 4; i++) {
        int v = t + 256 * i;
        int m = v >> 4, k4 = (v & 15) * 4;
        float4 x = *(const float4*)&A[(size_t)(m0 + m) * K + ks + k4];
        Asm[k4 + 0][m] = x.x; Asm[k4 + 1][m] = x.y;
        Asm[k4 + 2][m] = x.z; Asm[k4 + 3][m] = x.w;
    }
    #pragma unroll
    for (int i = 0; i < 4; i++) {
        int v = t + 256 * i;
        int r = v >> 4, c4 = (v & 15) * 4;
        *(float4*)&Bsm[r][c4] = *(const float4*)&B[(size_t)(ks + r) * N + n0 + c4];
    }
    __syncthreads();

    int r4 = (t >> 4) * 4, c4 = (t & 15) * 4;
    float acc[4][4] = {{0.f}};
    #pragma unroll
    for (int kk = 0; kk < GBK; kk++) {
        float4 a = *(const float4*)&Asm[kk][r4];
        float4 b = *(const float4*)&Bsm[kk][c4];
        float av[4] = {a.x, a.y, a.z, a.w};
        float bv[4] = {b.x, b.y, b.z, b.w};
        #pragma unroll
        for (int i = 0; i < 4; i++)
            #pragma unroll
            for (int j = 0; j < 4; j++) acc[i][j] += av[i] * bv[j];
    }
    float* Cp = Cpart + (size_t)blockIdx.z * M * N;
    #pragma unroll
    for (int i = 0; i < 4; i++) {
        float4 v = {acc[i][0], acc[i][1], acc[i][2], acc[i][3]};
        *(float4*)&Cp[(size_t)(m0 + r4 + i) * N + n0 + c4] = v;
    }
}

// ---- gemm2 fused: pz[s][M][N] partial of (sum_s py + b_ts)[M,K] @ W[N,K]^T ----
__global__ __launch_bounds__(256) void gemm2_fused(
    const float* __restrict__ py, const float* __restrict__ b_ts,
    const float* __restrict__ W, float* __restrict__ pz,
    int M, int N, int K, int S)
{
    __shared__ __align__(16) float Asm[GBK][GPAD];  // [kk][m], kk = h in slice
    __shared__ __align__(16) float Bsm[GBK][GPAD];  // [kk][n]
    int t  = threadIdx.x;
    int m0 = blockIdx.y * GBM, n0 = blockIdx.x * GBN;
    int ks = blockIdx.z * GBK;

    #pragma unroll
    for (int i = 0; i < 4; i++) {                    // A = reduced y tile
        int v = t + 256 * i;
        int m = v >> 4, h4 = (v & 15) * 4;
        float4 x = *(const float4*)&b_ts[ks + h4];
        for (int s = 0; s < S; s++) {
            float4 p = *(const float4*)&py[((size_t)s * M + m0 + m) * K + ks + h4];
            x.x += p.x; x.y += p.y; x.z += p.z; x.w += p.w;
        }
        Asm[h4 + 0][m] = x.x; Asm[h4 + 1][m] = x.y;
        Asm[h4 + 2][m] = x.z; Asm[h4 + 3][m] = x.w;
    }
    #pragma unroll
    for (int i = 0; i < 4; i++) {                    // B^T tile
        int v = t + 256 * i;
        int n = v >> 4, k4 = (v & 15) * 4;
        float4 x = *(const float4*)&W[(size_t)(n0 + n) * K + ks + k4];
        Bsm[k4 + 0][n] = x.x; Bsm[k4 + 1][n] = x.y;
        Bsm[k4 + 2][n] = x.z; Bsm[k4 + 3][n] = x.w;
    }
    __syncthreads();

    int r4 = (t >> 4) * 4, c4 = (t & 15) * 4;
    float acc[4][4] = {{0.f}};
    #pragma unroll
    for (int kk = 0; kk < GBK; kk++) {
        float4 a = *(const float4*)&Asm[kk][r4];
        float4 b = *(const float4*)&Bsm[kk][c4];
        float av[4] = {a.x, a.y, a.z, a.w};
        float bv[4] = {b.x, b.y, b.z, b.w};
        #pragma unroll
        for (int i = 0; i < 4; i++)
            #pragma unroll
            for (int j = 0; j < 4; j++) acc[i][j] += av[i] * bv[j];
    }
    float* Cp = pz + (size_t)blockIdx.z * M * N;
    #pragma unroll
    for (int i = 0; i < 4; i++) {
        float4 v = {acc[i][0], acc[i][1], acc[i][2], acc[i][3]};
        *(float4*)&Cp[(size_t)(m0 + r4 + i) * N + n0 + c4] = v;
    }
}

// ---- s_part[b,g,ds] = sum_{d in chunk ds} feat[b,d,g] * z[b,d] -------------
// z summed from split-K partials on load; feat staged via global_load_lds DMA,
// double-buffered, one barrier per 16-row group. (R4-proven structure.)
__global__ __launch_bounds__(256) void feat_dot(
    const float* __restrict__ feat, const float* __restrict__ zpart,
    float* __restrict__ s_part, int G, int D, int bs)
{
    const int b = blockIdx.y, ds = blockIdx.x;
    const int dchunk = D / DSPLIT;          // 128
    const int ngrp = dchunk / ROWG;         // 8
    const int grpVec = ROWG * G / 4;        // 676 float4 per group
    __shared__ float4 bufv[2][676];
    __shared__ __align__(16) float zs[128];
    int t  = threadIdx.x;
    int wb = t & ~63;                       // wave-uniform base

    if (t < dchunk) {
        float s = 0.f;
        #pragma unroll
        for (int sp = 0; sp < DSPLIT; sp++)
            s += zpart[((size_t)sp * bs + b) * D + ds * dchunk + t];
        zs[t] = s;
    }

    const float* gsrc = feat + ((size_t)b * D + (size_t)ds * dchunk) * G;
    {   // prologue: DMA group 0 into buffer 0
        float* dst = (float*)bufv[0];
        gload_lds16(gsrc + 4 * t,         dst + 4 * wb);
        gload_lds16(gsrc + 4 * (t + 256), dst + 4 * (wb + 256));
        if (t + 512 < grpVec)
            gload_lds16(gsrc + 4 * (t + 512), dst + 4 * (wb + 512));
    }
    __syncthreads();

    float acc = 0.f;
    int cur = 0;
    for (int gi = 0; gi < ngrp; gi++) {
        if (gi + 1 < ngrp) {                // issue next-group DMA first
            const float* gs = gsrc + (size_t)(gi + 1) * (grpVec * 4);
            float* dst = (float*)bufv[cur ^ 1];
            gload_lds16(gs + 4 * t,         dst + 4 * wb);
            gload_lds16(gs + 4 * (t + 256), dst + 4 * (wb + 256));
            if (t + 512 < grpVec)
                gload_lds16(gs + 4 * (t + 512), dst + 4 * (wb + 512));
        }
        if (t < G) {
            const float* bp = (const float*)bufv[cur];
            #pragma unroll
            for (int r4 = 0; r4 < ROWG / 4; r4++) {
                float4 zv = *(const float4*)&zs[gi * ROWG + r4 * 4];
                acc += bp[(r4 * 4 + 0) * G + t] * zv.x;
                acc += bp[(r4 * 4 + 1) * G + t] * zv.y;
                acc += bp[(r4 * 4 + 2) * G + t] * zv.z;
                acc += bp[(r4 * 4 + 3) * G + t] * zv.w;
            }
        }
        __syncthreads();                    // drains DMA for next buffer too
        cur ^= 1;
    }
    if (t < G) s_part[((size_t)b * G + t) * DSPLIT + ds] = acc;
}

// ---- per-batch finalize (py reduced inline; no fences, graph edge orders) --
__global__ __launch_bounds__(256) void finalize(
    const float* __restrict__ boxes, const float* __restrict__ masks,
    const float* __restrict__ s_part, const float* __restrict__ py,
    const float* __restrict__ b_ts, const float* __restrict__ b_vs,
    const int* __restrict__ kptr,
    float* __restrict__ out_box, float* __restrict__ out_mask,
    float* __restrict__ out_max,
    int G, int AN, int CH, int CM, int H, int bs, int S)
{
    __shared__ float ms[176];
    __shared__ int   selg[176];
    __shared__ float simv[176];
    __shared__ float redw[4];
    __shared__ float bb_s;
    __shared__ int   sel_pair[2];

    int b = blockIdx.x, t = threadIdx.x;
    int k = *kptr; if (k > G) k = G;

    if (t < G) {
        const float* bp = boxes + (size_t)(b * G + t) * AN * CH;
        float s = 0.f;
        for (int a = 0; a < AN; a++) s += bp[a * CH + 4];
        ms[t] = s / (float)AN;
    }
    // bb = b_vs . (sum_s py[s][b] + b_ts)
    float part = 0.f;
    for (int h = t; h < H; h += 256) {
        float yv = b_ts[h];
        for (int s = 0; s < S; s++) yv += py[((size_t)s * bs + b) * H + h];
        part += b_vs[h] * yv;
    }
    #pragma unroll
    for (int off = 32; off > 0; off >>= 1) part += __shfl_down(part, off);
    if ((t & 63) == 0) redw[t >> 6] = part;
    __syncthreads();
    if (t == 0) bb_s = redw[0] + redw[1] + redw[2] + redw[3];

    // exact top-k via rank (value desc, index asc) -- matches lax.top_k ties
    if (t < G) {
        float mv = ms[t];
        int rank = 0;
        for (int g = 0; g < G; g++) {
            float o = ms[g];
            rank += (int)((o > mv) | ((o == mv) & (g < t)));
        }
        if (rank < k) selg[rank] = t;
    }
    __syncthreads();

    if (t < k) {
        const float* sp = s_part + ((size_t)b * G + selg[t]) * DSPLIT;
        float s = 0.f;
        #pragma unroll
        for (int i = 0; i < DSPLIT; i++) s += sp[i];
        simv[t] = s;
    }
    __syncthreads();

    if (t == 0) {
        float best = -FLT_MAX; int br = 0;
        for (int r = 0; r < k; r++) if (simv[r] > best) { best = simv[r]; br = r; }
        int gs = selg[br];
        const float* bp = boxes + (size_t)(b * G + gs) * AN * CH;
        float bo = -FLT_MAX; int ai = 0;
        for (int a = 0; a < AN; a++) { float o = bp[a * CH + 4]; if (o > bo) { bo = o; ai = a; } }
        float cx = bp[ai * CH + 0], cy = bp[ai * CH + 1];
        float w  = bp[ai * CH + 2], hh = bp[ai * CH + 3];
        float x1 = cx - w * 0.5f, y1 = cy - hh * 0.5f;
        out_box[(size_t)b * CH + 0] = x1;
        out_box[(size_t)b * CH + 1] = y1;
        out_box[(size_t)b * CH + 2] = x1 + w;
        out_box[(size_t)b * CH + 3] = y1 + hh;
        for (int c = 4; c < CH; c++) out_box[(size_t)b * CH + c] = bp[ai * CH + c];
        out_max[b] = best + bb_s;
        sel_pair[0] = gs; sel_pair[1] = ai;
    }
    __syncthreads();
    if (t < CM) {
        out_mask[(size_t)b * CM + t] =
            masks[((size_t)(b * G + sel_pair[0]) * AN + sel_pair[1]) * CM + t];
    }
}

extern "C" void kernel_launch(void* const* d_in, const int* in_sizes, int n_in,
                              void* d_out, int out_size, void* d_ws, size_t ws_size,
                              hipStream_t stream)
{
    const float* boxes = (const float*)d_in[0];
    const float* masks = (const float*)d_in[1];
    const float* feat  = (const float*)d_in[2];
    const float* lang  = (const float*)d_in[3];
    const float* W_vs  = (const float*)d_in[4];
    const float* b_vs  = (const float*)d_in[5];
    const float* W_ts  = (const float*)d_in[6];
    const float* b_ts  = (const float*)d_in[7];
    const int*   kptr  = (const int*)d_in[8];

    int H  = in_sizes[5];                 // 512
    int D  = in_sizes[4] / H;             // 1024
    int bs = in_sizes[3] / H;             // 256
    int G  = in_sizes[2] / (bs * D);      // 169
    int AN = 3;
    int CH = in_sizes[0] / (bs * G * AN); // 5
    int CM = in_sizes[1] / (bs * G * AN); // 32
    const int S = 8;                      // split-K slices (K = 512 = S*64)

    float* py     = (float*)d_ws;                       // S*bs*H
    float* pz     = py + (size_t)S * bs * H;            // S*bs*D
    float* s_part = pz + (size_t)S * bs * D;            // bs*G*DSPLIT

    float* out_box  = (float*)d_out;
    float* out_mask = out_box + (size_t)bs * CH;
    float* out_max  = out_mask + (size_t)bs * CM;

    // py = split-K partials of lang @ W_ts
    dim3 g1(H / GBN, bs / GBM, S);
    gemm_splitk<<<g1, 256, 0, stream>>>(lang, W_ts, py, bs, H, H);
    // pz = split-K partials of (sum py + b_ts) @ W_vs^T
    dim3 g2(D / GBN, bs / GBM, S);
    gemm2_fused<<<g2, 256, 0, stream>>>(py, b_ts, W_vs, pz, bs, D, H, S);
    // s_part = partial feat . z
    dim3 gC(DSPLIT, bs);
    feat_dot<<<gC, 256, 0, stream>>>(feat, pz, s_part, G, D, bs);
    // finalize per batch
    finalize<<<bs, 256, 0, stream>>>(boxes, masks, s_part, py, b_ts, b_vs, kptr,
                                     out_box, out_mask, out_max,
                                     G, AN, CH, CM, H, bs, S);
}